// Round 2
// baseline (1959.110 us; speedup 1.0000x reference)
//
#include <hip/hip_runtime.h>

#define NN 50000
#define NE 800000
#define SCAN_NB ((NN + 255) / 256)   // 196

// ---------------------------------------------------------------- utilities
__global__ void zero_int_kernel(int* __restrict__ p, int n) {
    int i = blockIdx.x * blockDim.x + threadIdx.x;
    if (i < n) p[i] = 0;
}

// ---------------------------------------------------------------- CSR build
__global__ void deg_kernel(const int* __restrict__ dst, int* __restrict__ deg, int E) {
    int e = blockIdx.x * blockDim.x + threadIdx.x;
    if (e < E) atomicAdd(&deg[dst[e]], 1);
}

// phase 1: per-block inclusive scan; write exclusive prefix (no global offset) + block sum
__global__ void scan1_kernel(const int* __restrict__ deg, int* __restrict__ pre,
                             int* __restrict__ bsum) {
    __shared__ int sm[256];
    int t = threadIdx.x;
    int i = blockIdx.x * 256 + t;
    int v = (i < NN) ? deg[i] : 0;
    sm[t] = v;
    __syncthreads();
#pragma unroll
    for (int off = 1; off < 256; off <<= 1) {
        int u = (t >= off) ? sm[t - off] : 0;
        __syncthreads();
        sm[t] += u;
        __syncthreads();
    }
    if (i < NN) pre[i] = sm[t] - v;          // exclusive within block
    if (t == 255) bsum[blockIdx.x] = sm[255];
}

// phase 2: single small block scans the 196 block sums -> exclusive offsets
__global__ void scan2_kernel(const int* __restrict__ bsum, int* __restrict__ boff) {
    __shared__ int sm[256];
    int t = threadIdx.x;
    int v = (t < SCAN_NB) ? bsum[t] : 0;
    sm[t] = v;
    __syncthreads();
#pragma unroll
    for (int off = 1; off < 256; off <<= 1) {
        int u = (t >= off) ? sm[t - off] : 0;
        __syncthreads();
        sm[t] += u;
        __syncthreads();
    }
    if (t < SCAN_NB) boff[t] = sm[t] - v;
}

// phase 3: add block offsets, produce row_start + cursor
__global__ void scan3_kernel(int* __restrict__ row_start, const int* __restrict__ boff,
                             int* __restrict__ cursor) {
    int i = blockIdx.x * 256 + threadIdx.x;
    if (i < NN) {
        int r = row_start[i] + boff[blockIdx.x];
        row_start[i] = r;
        cursor[i] = r;
    }
    if (i == 0) row_start[NN] = NE;
}

__global__ void fill_kernel(const int* __restrict__ src, const int* __restrict__ dst,
                            int* __restrict__ cursor, int* __restrict__ csr_src,
                            int* __restrict__ csr_eid, int E) {
    int e = blockIdx.x * blockDim.x + threadIdx.x;
    if (e < E) {
        int d = dst[e];
        int p = atomicAdd(&cursor[d], 1);
        csr_src[p] = src[e];
        csr_eid[p] = e;
    }
}

// ---------------------------------------------------------------- agg_e (once)
__global__ void agge_kernel(const float* __restrict__ ea, const int* __restrict__ row_start,
                            const int* __restrict__ eid, float* __restrict__ aggE) {
    int v = blockIdx.x * blockDim.x + threadIdx.x;
    if (v >= NN) return;
    float4 a0 = {0.f, 0.f, 0.f, 0.f}, a1 = {0.f, 0.f, 0.f, 0.f};
    int lo = row_start[v], hi = row_start[v + 1];
    for (int j = lo; j < hi; ++j) {
        int e = eid[j];
        const float4* p = reinterpret_cast<const float4*>(ea + (size_t)e * 8);
        float4 u = p[0], w = p[1];
        a0.x += u.x; a0.y += u.y; a0.z += u.z; a0.w += u.w;
        a1.x += w.x; a1.y += w.y; a1.z += w.z; a1.w += w.w;
    }
    float4* o = reinterpret_cast<float4*>(aggE + (size_t)v * 8);
    o[0] = a0; o[1] = a1;
}

// ---------------------------------------------------------------- agg_h (per layer)
// wave per node, no atomics, 2-edge unroll for load ILP
template <int DIN>
__global__ void aggh_kernel(const float* __restrict__ h, const int* __restrict__ row_start,
                            const int* __restrict__ csrc, float* __restrict__ aggH) {
    int w = blockIdx.x * (blockDim.x >> 6) + (threadIdx.x >> 6);
    int lane = threadIdx.x & 63;
    if (w >= NN) return;
    int lo = row_start[w], hi = row_start[w + 1];
    if constexpr (DIN == 128) {
        float2 acc0 = {0.f, 0.f}, acc1 = {0.f, 0.f};
        const float2* H = reinterpret_cast<const float2*>(h);
        int j = lo;
        for (; j + 1 < hi; j += 2) {
            int s0 = csrc[j], s1 = csrc[j + 1];
            float2 v0 = H[(size_t)s0 * 64 + lane];
            float2 v1 = H[(size_t)s1 * 64 + lane];
            acc0.x += v0.x; acc0.y += v0.y;
            acc1.x += v1.x; acc1.y += v1.y;
        }
        if (j < hi) {
            int s0 = csrc[j];
            float2 v0 = H[(size_t)s0 * 64 + lane];
            acc0.x += v0.x; acc0.y += v0.y;
        }
        acc0.x += acc1.x; acc0.y += acc1.y;
        reinterpret_cast<float2*>(aggH)[(size_t)w * 64 + lane] = acc0;
    } else if constexpr (DIN == 64) {
        float acc0 = 0.f, acc1 = 0.f;
        int j = lo;
        for (; j + 1 < hi; j += 2) {
            int s0 = csrc[j], s1 = csrc[j + 1];
            acc0 += h[(size_t)s0 * 64 + lane];
            acc1 += h[(size_t)s1 * 64 + lane];
        }
        if (j < hi) acc0 += h[(size_t)csrc[j] * 64 + lane];
        aggH[(size_t)w * 64 + lane] = acc0 + acc1;
    } else {  // DIN == 32
        if (lane < 32) {
            float acc0 = 0.f, acc1 = 0.f;
            int j = lo;
            for (; j + 1 < hi; j += 2) {
                int s0 = csrc[j], s1 = csrc[j + 1];
                acc0 += h[(size_t)s0 * 32 + lane];
                acc1 += h[(size_t)s1 * 32 + lane];
            }
            if (j < hi) acc0 += h[(size_t)csrc[j] * 32 + lane];
            aggH[(size_t)w * 32 + lane] = acc0 + acc1;
        }
    }
}

// ---------------------------------------------------------------- fused dense layer
// out[n,:] = relu( h[n,:]@Ws + aggH[n,:]@Wm[0:DIN] + aggE[n,:]@Wm[DIN:DIN+8] + b )
// 256 threads; tile 64 rows x DOUT cols; thread = 4 rows x (DOUT/16) cols; K-chunk 16
template <int DIN, int DOUT>
__global__ __launch_bounds__(256, 3) void dense_kernel(
    const float* __restrict__ h, const float* __restrict__ aggH, const float* __restrict__ aggE,
    const float* __restrict__ Ws, const float* __restrict__ Wm, const float* __restrict__ b,
    float* __restrict__ out) {
    constexpr int K = 2 * DIN + 8;
    constexpr int NCH = (K + 15) / 16;
    constexpr int TN = DOUT / 16;   // 4 or 8 cols per thread
    constexpr int NCP = TN / 2;     // float2 col pairs
    __shared__ float Xs[16][68];    // [k][row], 272B row stride (16B multiple)
    __shared__ float Wsh[16][DOUT];
    int t = threadIdx.x;
    int tn = t & 15, tm = t >> 4;   // 16 col-threads x 16 row-threads
    int row0 = blockIdx.x * 64;

    float acc[4][TN];
#pragma unroll
    for (int r = 0; r < 4; ++r)
#pragma unroll
        for (int c = 0; c < TN; ++c) acc[r][c] = 0.f;

    for (int ch = 0; ch < NCH; ++ch) {
        int k0 = ch * 16;
        // stage X: 64 rows x 16 k = 1024 floats (4/thread), coalesced 64B runs
#pragma unroll
        for (int rep = 0; rep < 4; ++rep) {
            int idx = rep * 256 + t;
            int r = idx >> 4, k = idx & 15;
            int row = row0 + r, kk = k0 + k;
            float v = 0.f;
            if (row < NN && kk < K) {
                if (kk < DIN)          v = h[(size_t)row * DIN + kk];
                else if (kk < 2 * DIN) v = aggH[(size_t)row * DIN + (kk - DIN)];
                else                   v = aggE[(size_t)row * 8 + (kk - 2 * DIN)];
            }
            Xs[k][r] = v;
        }
        // stage W: 16 x DOUT floats (DOUT/16 per thread), fully coalesced
#pragma unroll
        for (int rep = 0; rep < DOUT / 16; ++rep) {
            int idx = rep * 256 + t;
            int k = idx / DOUT, c = idx % DOUT;
            int kk = k0 + k;
            float v = 0.f;
            if (kk < DIN)      v = Ws[(size_t)kk * DOUT + c];
            else if (kk < K)   v = Wm[(size_t)(kk - DIN) * DOUT + c];
            Wsh[k][c] = v;
        }
        __syncthreads();
#pragma unroll
        for (int k = 0; k < 16; ++k) {
            float4 xq = *reinterpret_cast<const float4*>(&Xs[k][tm * 4]);
            float xv[4] = {xq.x, xq.y, xq.z, xq.w};
            float2 wv[NCP];
#pragma unroll
            for (int cp = 0; cp < NCP; ++cp)
                wv[cp] = *reinterpret_cast<const float2*>(&Wsh[k][cp * 32 + tn * 2]);
#pragma unroll
            for (int r = 0; r < 4; ++r)
#pragma unroll
                for (int cp = 0; cp < NCP; ++cp) {
                    acc[r][2 * cp]     += xv[r] * wv[cp].x;
                    acc[r][2 * cp + 1] += xv[r] * wv[cp].y;
                }
        }
        __syncthreads();
    }
    // epilogue: bias + relu + float2 store
#pragma unroll
    for (int r = 0; r < 4; ++r) {
        int row = row0 + tm * 4 + r;
        if (row < NN) {
#pragma unroll
            for (int cp = 0; cp < NCP; ++cp) {
                int col = cp * 32 + tn * 2;
                float2 v;
                v.x = acc[r][2 * cp]     + b[col];
                v.y = acc[r][2 * cp + 1] + b[col + 1];
                v.x = v.x > 0.f ? v.x : 0.f;
                v.y = v.y > 0.f ? v.y : 0.f;
                *reinterpret_cast<float2*>(&out[(size_t)row * DOUT + col]) = v;
            }
        }
    }
}

// ---------------------------------------------------------------- final linear
__global__ void final_kernel(const float* __restrict__ h, const float* __restrict__ Wc,
                             const float* __restrict__ bc, float* __restrict__ out) {
    int w = blockIdx.x * (blockDim.x >> 6) + (threadIdx.x >> 6);
    int lane = threadIdx.x & 63;
    if (w >= NN) return;
    const float2* H = reinterpret_cast<const float2*>(h);
    const float2* W = reinterpret_cast<const float2*>(Wc);
    float2 hv = H[(size_t)w * 64 + lane];
    float2 wv = W[lane];
    float p = hv.x * wv.x + hv.y * wv.y;
#pragma unroll
    for (int off = 32; off; off >>= 1) p += __shfl_down(p, off);
    if (lane == 0) out[w] = p + bc[0];
}

// ---------------------------------------------------------------- launch
extern "C" void kernel_launch(void* const* d_in, const int* in_sizes, int n_in,
                              void* d_out, int out_size, void* d_ws, size_t ws_size,
                              hipStream_t stream) {
    const float* x   = (const float*)d_in[0];
    const float* ea  = (const float*)d_in[1];
    const int*   src = (const int*)d_in[2];
    const int*   dst = (const int*)d_in[3];
    const float* Ws[5]; const float* Wm[5]; const float* bb[5];
    for (int i = 0; i < 5; ++i) {
        Ws[i] = (const float*)d_in[4 + 3 * i];
        Wm[i] = (const float*)d_in[5 + 3 * i];
        bb[i] = (const float*)d_in[6 + 3 * i];
    }
    const float* Wc = (const float*)d_in[19];
    const float* bc = (const float*)d_in[20];
    float* out = (float*)d_out;

    size_t off = 0;
    auto alloc = [&](size_t bytes) {
        void* p = (char*)d_ws + off;
        off += (bytes + 255) & ~(size_t)255;
        return p;
    };
    float* hA        = (float*)alloc((size_t)NN * 128 * 4);
    float* hB        = (float*)alloc((size_t)NN * 128 * 4);
    float* aggH      = (float*)alloc((size_t)NN * 128 * 4);
    float* aggE      = (float*)alloc((size_t)NN * 8 * 4);
    int*   deg       = (int*)alloc((size_t)(NN + 1) * 4);
    int*   row_start = (int*)alloc((size_t)(NN + 1) * 4);
    int*   cursor    = (int*)alloc((size_t)NN * 4);
    int*   csr_src   = (int*)alloc((size_t)NE * 4);
    int*   csr_eid   = (int*)alloc((size_t)NE * 4);
    int*   bsum      = (int*)alloc((size_t)SCAN_NB * 4);
    int*   boff      = (int*)alloc((size_t)SCAN_NB * 4);
    (void)ws_size; (void)in_sizes; (void)n_in; (void)out_size;

    // CSR build (per launch — no cached state)
    zero_int_kernel<<<(NN + 255) / 256, 256, 0, stream>>>(deg, NN);
    deg_kernel<<<(NE + 255) / 256, 256, 0, stream>>>(dst, deg, NE);
    scan1_kernel<<<SCAN_NB, 256, 0, stream>>>(deg, row_start, bsum);
    scan2_kernel<<<1, 256, 0, stream>>>(bsum, boff);
    scan3_kernel<<<SCAN_NB, 256, 0, stream>>>(row_start, boff, cursor);
    fill_kernel<<<(NE + 255) / 256, 256, 0, stream>>>(src, dst, cursor, csr_src, csr_eid, NE);

    // edge-attr aggregation (layer-independent)
    agge_kernel<<<(NN + 255) / 256, 256, 0, stream>>>(ea, row_start, csr_eid, aggE);

    const int GRID_W = (NN + 3) / 4;       // wave-per-node kernels (4 waves/block)
    const int GRID_D = (NN + 63) / 64;     // dense kernels

    // layer 0: 32 -> 64
    aggh_kernel<32><<<GRID_W, 256, 0, stream>>>(x, row_start, csr_src, aggH);
    dense_kernel<32, 64><<<GRID_D, 256, 0, stream>>>(x, aggH, aggE, Ws[0], Wm[0], bb[0], hA);
    // layer 1: 64 -> 128
    aggh_kernel<64><<<GRID_W, 256, 0, stream>>>(hA, row_start, csr_src, aggH);
    dense_kernel<64, 128><<<GRID_D, 256, 0, stream>>>(hA, aggH, aggE, Ws[1], Wm[1], bb[1], hB);
    // layer 2: 128 -> 128
    aggh_kernel<128><<<GRID_W, 256, 0, stream>>>(hB, row_start, csr_src, aggH);
    dense_kernel<128, 128><<<GRID_D, 256, 0, stream>>>(hB, aggH, aggE, Ws[2], Wm[2], bb[2], hA);
    // layer 3: 128 -> 128
    aggh_kernel<128><<<GRID_W, 256, 0, stream>>>(hA, row_start, csr_src, aggH);
    dense_kernel<128, 128><<<GRID_D, 256, 0, stream>>>(hA, aggH, aggE, Ws[3], Wm[3], bb[3], hB);
    // layer 4: 128 -> 128
    aggh_kernel<128><<<GRID_W, 256, 0, stream>>>(hB, row_start, csr_src, aggH);
    dense_kernel<128, 128><<<GRID_D, 256, 0, stream>>>(hB, aggH, aggE, Ws[4], Wm[4], bb[4], hA);

    // readout
    final_kernel<<<GRID_W, 256, 0, stream>>>(hA, Wc, bc, out);
}

// Round 3
// 661.794 us; speedup vs baseline: 2.9603x; 2.9603x over previous
//
#include <hip/hip_runtime.h>

#define NN 50000
#define NE 800000
#define SCAN_NB ((NN + 255) / 256)   // 196

// ---------------------------------------------------------------- utilities
__global__ void zero_int_kernel(int* __restrict__ p, int n) {
    int i = blockIdx.x * blockDim.x + threadIdx.x;
    if (i < n) p[i] = 0;
}

// ---------------------------------------------------------------- CSR build
__global__ void deg_kernel(const int* __restrict__ dst, int* __restrict__ deg, int E) {
    int e = blockIdx.x * blockDim.x + threadIdx.x;
    if (e < E) atomicAdd(&deg[dst[e]], 1);
}

__global__ void scan1_kernel(const int* __restrict__ deg, int* __restrict__ pre,
                             int* __restrict__ bsum) {
    __shared__ int sm[256];
    int t = threadIdx.x;
    int i = blockIdx.x * 256 + t;
    int v = (i < NN) ? deg[i] : 0;
    sm[t] = v;
    __syncthreads();
#pragma unroll
    for (int off = 1; off < 256; off <<= 1) {
        int u = (t >= off) ? sm[t - off] : 0;
        __syncthreads();
        sm[t] += u;
        __syncthreads();
    }
    if (i < NN) pre[i] = sm[t] - v;
    if (t == 255) bsum[blockIdx.x] = sm[255];
}

__global__ void scan2_kernel(const int* __restrict__ bsum, int* __restrict__ boff) {
    __shared__ int sm[256];
    int t = threadIdx.x;
    int v = (t < SCAN_NB) ? bsum[t] : 0;
    sm[t] = v;
    __syncthreads();
#pragma unroll
    for (int off = 1; off < 256; off <<= 1) {
        int u = (t >= off) ? sm[t - off] : 0;
        __syncthreads();
        sm[t] += u;
        __syncthreads();
    }
    if (t < SCAN_NB) boff[t] = sm[t] - v;
}

__global__ void scan3_kernel(int* __restrict__ row_start, const int* __restrict__ boff,
                             int* __restrict__ cursor) {
    int i = blockIdx.x * 256 + threadIdx.x;
    if (i < NN) {
        int r = row_start[i] + boff[blockIdx.x];
        row_start[i] = r;
        cursor[i] = r;
    }
    if (i == 0) row_start[NN] = NE;
}

__global__ void fill_kernel(const int* __restrict__ src, const int* __restrict__ dst,
                            int* __restrict__ cursor, int* __restrict__ csr_src,
                            int* __restrict__ csr_eid, int E) {
    int e = blockIdx.x * blockDim.x + threadIdx.x;
    if (e < E) {
        int d = dst[e];
        int p = atomicAdd(&cursor[d], 1);
        csr_src[p] = src[e];
        csr_eid[p] = e;
    }
}

// ---------------------------------------------------------------- agg_e (once)
__global__ void agge_kernel(const float* __restrict__ ea, const int* __restrict__ row_start,
                            const int* __restrict__ eid, float* __restrict__ aggE) {
    int v = blockIdx.x * blockDim.x + threadIdx.x;
    if (v >= NN) return;
    float4 a0 = {0.f, 0.f, 0.f, 0.f}, a1 = {0.f, 0.f, 0.f, 0.f};
    int lo = row_start[v], hi = row_start[v + 1];
    for (int j = lo; j < hi; ++j) {
        int e = eid[j];
        const float4* p = reinterpret_cast<const float4*>(ea + (size_t)e * 8);
        float4 u = p[0], w = p[1];
        a0.x += u.x; a0.y += u.y; a0.z += u.z; a0.w += u.w;
        a1.x += w.x; a1.y += w.y; a1.z += w.z; a1.w += w.w;
    }
    float4* o = reinterpret_cast<float4*>(aggE + (size_t)v * 8);
    o[0] = a0; o[1] = a1;
}

// ---------------------------------------------------------------- agg_h (per layer)
template <int DIN>
__global__ void aggh_kernel(const float* __restrict__ h, const int* __restrict__ row_start,
                            const int* __restrict__ csrc, float* __restrict__ aggH) {
    int w = blockIdx.x * (blockDim.x >> 6) + (threadIdx.x >> 6);
    int lane = threadIdx.x & 63;
    if (w >= NN) return;
    int lo = row_start[w], hi = row_start[w + 1];
    if constexpr (DIN == 128) {
        float2 acc0 = {0.f, 0.f}, acc1 = {0.f, 0.f};
        const float2* H = reinterpret_cast<const float2*>(h);
        int j = lo;
        for (; j + 1 < hi; j += 2) {
            int s0 = csrc[j], s1 = csrc[j + 1];
            float2 v0 = H[(size_t)s0 * 64 + lane];
            float2 v1 = H[(size_t)s1 * 64 + lane];
            acc0.x += v0.x; acc0.y += v0.y;
            acc1.x += v1.x; acc1.y += v1.y;
        }
        if (j < hi) {
            int s0 = csrc[j];
            float2 v0 = H[(size_t)s0 * 64 + lane];
            acc0.x += v0.x; acc0.y += v0.y;
        }
        acc0.x += acc1.x; acc0.y += acc1.y;
        reinterpret_cast<float2*>(aggH)[(size_t)w * 64 + lane] = acc0;
    } else if constexpr (DIN == 64) {
        float acc0 = 0.f, acc1 = 0.f;
        int j = lo;
        for (; j + 1 < hi; j += 2) {
            int s0 = csrc[j], s1 = csrc[j + 1];
            acc0 += h[(size_t)s0 * 64 + lane];
            acc1 += h[(size_t)s1 * 64 + lane];
        }
        if (j < hi) acc0 += h[(size_t)csrc[j] * 64 + lane];
        aggH[(size_t)w * 64 + lane] = acc0 + acc1;
    } else {  // DIN == 32
        if (lane < 32) {
            float acc0 = 0.f, acc1 = 0.f;
            int j = lo;
            for (; j + 1 < hi; j += 2) {
                int s0 = csrc[j], s1 = csrc[j + 1];
                acc0 += h[(size_t)s0 * 32 + lane];
                acc1 += h[(size_t)s1 * 32 + lane];
            }
            if (j < hi) acc0 += h[(size_t)csrc[j] * 32 + lane];
            aggH[(size_t)w * 32 + lane] = acc0 + acc1;
        }
    }
}

// ---------------------------------------------------------------- fused dense layer
// out = relu( h@Ws + aggH@Wm[0:DIN] + aggE@Wm[DIN:DIN+8] + b )
// 64 rows x DOUT cols per block, 256 threads (16 col x 16 row groups),
// thread tile 4 rows x (DOUT/16) cols. K chunked by 32, each chunk from ONE src.
// ALL global accesses are float4 with 64-lane-contiguous 1KB runs.
template <int DIN, int DOUT>
__global__ __launch_bounds__(256) void dense_kernel(
    const float* __restrict__ h, const float* __restrict__ aggH, const float* __restrict__ aggE,
    const float* __restrict__ Ws, const float* __restrict__ Wm, const float* __restrict__ b,
    float* __restrict__ out) {
    constexpr int NCH = DIN / 16;        // 2*DIN/32 chunks over [h | aggH]
    constexpr int HCH = DIN / 32;        // chunks belonging to h
    constexpr int TN = DOUT / 16;        // 4 or 8 cols per thread
    constexpr int NV = TN / 4;           // float4 col groups: 1 or 2

    __shared__ float Xs[64][36];         // [row][k], padded; 16B-aligned rows (144B)
    __shared__ float Wt[32][DOUT];       // [k][col]
    __shared__ float Es[64][8];          // aggE tile
    __shared__ float We[8][DOUT];        // Wm rows DIN..DIN+7

    const int t = threadIdx.x;
    const int tn = t & 15, tm = t >> 4;
    const int row0 = blockIdx.x * 64;

    // one-time stage: aggE tile (64x8) + We (8xDOUT) — all float4, contiguous
    if (t < 128) {
        int r = t >> 1, c4 = (t & 1) * 4;
        int row = row0 + r;
        float4 v = {0.f, 0.f, 0.f, 0.f};
        if (row < NN) v = *reinterpret_cast<const float4*>(&aggE[(size_t)row * 8 + c4]);
        *reinterpret_cast<float4*>(&Es[r][c4]) = v;
    }
    {
        constexpr int WE_F4 = 8 * DOUT / 4;   // 128 or 256
        if (t < WE_F4) {
            int k = t / (DOUT / 4), c4 = (t % (DOUT / 4)) * 4;
            *reinterpret_cast<float4*>(&We[k][c4]) =
                *reinterpret_cast<const float4*>(&Wm[(size_t)(DIN + k) * DOUT + c4]);
        }
    }

    float4 bv[NV];
#pragma unroll
    for (int g = 0; g < NV; ++g)
        bv[g] = *reinterpret_cast<const float4*>(&b[g * 64 + tn * 4]);

    float acc[4][TN];
#pragma unroll
    for (int r = 0; r < 4; ++r)
#pragma unroll
        for (int c = 0; c < TN; ++c) acc[r][c] = 0.f;

    for (int ch = 0; ch < NCH; ++ch) {
        const bool isH = (ch < HCH);
        const float* xsrc = isH ? h : aggH;
        const int koff = (isH ? ch : ch - HCH) * 32;
        const float* wsrc = isH ? (Ws + (size_t)(ch * 32) * DOUT)
                                : (Wm + (size_t)((ch - HCH) * 32) * DOUT);
        // X: 64 rows x 32 k = 512 float4, 2 per thread; 8 lanes cover one 128B row-chunk
#pragma unroll
        for (int rep = 0; rep < 2; ++rep) {
            int f4 = rep * 256 + t;
            int r = f4 >> 3, kof = (f4 & 7) * 4;
            int row = row0 + r;
            float4 v = {0.f, 0.f, 0.f, 0.f};
            if (row < NN)
                v = *reinterpret_cast<const float4*>(&xsrc[(size_t)row * DIN + koff + kof]);
            *reinterpret_cast<float4*>(&Xs[r][kof]) = v;
        }
        // W: 32 x DOUT = W_F4 float4, fully contiguous
        constexpr int W_F4 = 32 * DOUT / 4;  // 512 or 1024
#pragma unroll
        for (int rep = 0; rep < W_F4 / 256; ++rep) {
            int f4 = rep * 256 + t;
            int k = f4 / (DOUT / 4), c4 = (f4 % (DOUT / 4)) * 4;
            *reinterpret_cast<float4*>(&Wt[k][c4]) =
                *reinterpret_cast<const float4*>(&wsrc[(size_t)k * DOUT + c4]);
        }
        __syncthreads();
#pragma unroll
        for (int k = 0; k < 32; ++k) {
            float xv[4];
#pragma unroll
            for (int r = 0; r < 4; ++r) xv[r] = Xs[tm * 4 + r][k];
            float4 wv[NV];
#pragma unroll
            for (int g = 0; g < NV; ++g)
                wv[g] = *reinterpret_cast<const float4*>(&Wt[k][g * 64 + tn * 4]);
#pragma unroll
            for (int r = 0; r < 4; ++r)
#pragma unroll
                for (int g = 0; g < NV; ++g) {
                    acc[r][g * 4 + 0] += xv[r] * wv[g].x;
                    acc[r][g * 4 + 1] += xv[r] * wv[g].y;
                    acc[r][g * 4 + 2] += xv[r] * wv[g].z;
                    acc[r][g * 4 + 3] += xv[r] * wv[g].w;
                }
        }
        __syncthreads();
    }

    // aggE contribution (K=8)
#pragma unroll
    for (int j = 0; j < 8; ++j) {
        float xv[4];
#pragma unroll
        for (int r = 0; r < 4; ++r) xv[r] = Es[tm * 4 + r][j];
        float4 wv[NV];
#pragma unroll
        for (int g = 0; g < NV; ++g)
            wv[g] = *reinterpret_cast<const float4*>(&We[j][g * 64 + tn * 4]);
#pragma unroll
        for (int r = 0; r < 4; ++r)
#pragma unroll
            for (int g = 0; g < NV; ++g) {
                acc[r][g * 4 + 0] += xv[r] * wv[g].x;
                acc[r][g * 4 + 1] += xv[r] * wv[g].y;
                acc[r][g * 4 + 2] += xv[r] * wv[g].z;
                acc[r][g * 4 + 3] += xv[r] * wv[g].w;
            }
    }

    // epilogue: bias + relu + float4 store (16 lanes -> 256B contiguous)
#pragma unroll
    for (int r = 0; r < 4; ++r) {
        int row = row0 + tm * 4 + r;
        if (row < NN) {
#pragma unroll
            for (int g = 0; g < NV; ++g) {
                float4 o;
                o.x = acc[r][g * 4 + 0] + bv[g].x;
                o.y = acc[r][g * 4 + 1] + bv[g].y;
                o.z = acc[r][g * 4 + 2] + bv[g].z;
                o.w = acc[r][g * 4 + 3] + bv[g].w;
                o.x = o.x > 0.f ? o.x : 0.f;
                o.y = o.y > 0.f ? o.y : 0.f;
                o.z = o.z > 0.f ? o.z : 0.f;
                o.w = o.w > 0.f ? o.w : 0.f;
                *reinterpret_cast<float4*>(&out[(size_t)row * DOUT + g * 64 + tn * 4]) = o;
            }
        }
    }
}

// ---------------------------------------------------------------- final linear
__global__ void final_kernel(const float* __restrict__ h, const float* __restrict__ Wc,
                             const float* __restrict__ bc, float* __restrict__ out) {
    int w = blockIdx.x * (blockDim.x >> 6) + (threadIdx.x >> 6);
    int lane = threadIdx.x & 63;
    if (w >= NN) return;
    const float2* H = reinterpret_cast<const float2*>(h);
    const float2* W = reinterpret_cast<const float2*>(Wc);
    float2 hv = H[(size_t)w * 64 + lane];
    float2 wv = W[lane];
    float p = hv.x * wv.x + hv.y * wv.y;
#pragma unroll
    for (int off = 32; off; off >>= 1) p += __shfl_down(p, off);
    if (lane == 0) out[w] = p + bc[0];
}

// ---------------------------------------------------------------- launch
extern "C" void kernel_launch(void* const* d_in, const int* in_sizes, int n_in,
                              void* d_out, int out_size, void* d_ws, size_t ws_size,
                              hipStream_t stream) {
    const float* x   = (const float*)d_in[0];
    const float* ea  = (const float*)d_in[1];
    const int*   src = (const int*)d_in[2];
    const int*   dst = (const int*)d_in[3];
    const float* Ws[5]; const float* Wm[5]; const float* bb[5];
    for (int i = 0; i < 5; ++i) {
        Ws[i] = (const float*)d_in[4 + 3 * i];
        Wm[i] = (const float*)d_in[5 + 3 * i];
        bb[i] = (const float*)d_in[6 + 3 * i];
    }
    const float* Wc = (const float*)d_in[19];
    const float* bc = (const float*)d_in[20];
    float* out = (float*)d_out;

    size_t off = 0;
    auto alloc = [&](size_t bytes) {
        void* p = (char*)d_ws + off;
        off += (bytes + 255) & ~(size_t)255;
        return p;
    };
    float* hA        = (float*)alloc((size_t)NN * 128 * 4);
    float* hB        = (float*)alloc((size_t)NN * 128 * 4);
    float* aggH      = (float*)alloc((size_t)NN * 128 * 4);
    float* aggE      = (float*)alloc((size_t)NN * 8 * 4);
    int*   deg       = (int*)alloc((size_t)(NN + 1) * 4);
    int*   row_start = (int*)alloc((size_t)(NN + 1) * 4);
    int*   cursor    = (int*)alloc((size_t)NN * 4);
    int*   csr_src   = (int*)alloc((size_t)NE * 4);
    int*   csr_eid   = (int*)alloc((size_t)NE * 4);
    int*   bsum      = (int*)alloc((size_t)SCAN_NB * 4);
    int*   boff      = (int*)alloc((size_t)SCAN_NB * 4);
    (void)ws_size; (void)in_sizes; (void)n_in; (void)out_size;

    zero_int_kernel<<<(NN + 255) / 256, 256, 0, stream>>>(deg, NN);
    deg_kernel<<<(NE + 255) / 256, 256, 0, stream>>>(dst, deg, NE);
    scan1_kernel<<<SCAN_NB, 256, 0, stream>>>(deg, row_start, bsum);
    scan2_kernel<<<1, 256, 0, stream>>>(bsum, boff);
    scan3_kernel<<<SCAN_NB, 256, 0, stream>>>(row_start, boff, cursor);
    fill_kernel<<<(NE + 255) / 256, 256, 0, stream>>>(src, dst, cursor, csr_src, csr_eid, NE);

    agge_kernel<<<(NN + 255) / 256, 256, 0, stream>>>(ea, row_start, csr_eid, aggE);

    const int GRID_W = (NN + 3) / 4;
    const int GRID_D = (NN + 63) / 64;

    aggh_kernel<32><<<GRID_W, 256, 0, stream>>>(x, row_start, csr_src, aggH);
    dense_kernel<32, 64><<<GRID_D, 256, 0, stream>>>(x, aggH, aggE, Ws[0], Wm[0], bb[0], hA);

    aggh_kernel<64><<<GRID_W, 256, 0, stream>>>(hA, row_start, csr_src, aggH);
    dense_kernel<64, 128><<<GRID_D, 256, 0, stream>>>(hA, aggH, aggE, Ws[1], Wm[1], bb[1], hB);

    aggh_kernel<128><<<GRID_W, 256, 0, stream>>>(hB, row_start, csr_src, aggH);
    dense_kernel<128, 128><<<GRID_D, 256, 0, stream>>>(hB, aggH, aggE, Ws[2], Wm[2], bb[2], hA);

    aggh_kernel<128><<<GRID_W, 256, 0, stream>>>(hA, row_start, csr_src, aggH);
    dense_kernel<128, 128><<<GRID_D, 256, 0, stream>>>(hA, aggH, aggE, Ws[3], Wm[3], bb[3], hB);

    aggh_kernel<128><<<GRID_W, 256, 0, stream>>>(hB, row_start, csr_src, aggH);
    dense_kernel<128, 128><<<GRID_D, 256, 0, stream>>>(hB, aggH, aggE, Ws[4], Wm[4], bb[4], hA);

    final_kernel<<<GRID_W, 256, 0, stream>>>(hA, Wc, bc, out);
}

// Round 4
// 554.039 us; speedup vs baseline: 3.5360x; 1.1945x over previous
//
#include <hip/hip_runtime.h>

#define NN 50000
#define NE 800000
#define SCAN_NB ((NN + 255) / 256)   // 196

// ---------------------------------------------------------------- utilities
__global__ void zero_int_kernel(int* __restrict__ p, int n) {
    int i = blockIdx.x * blockDim.x + threadIdx.x;
    if (i < n) p[i] = 0;
}

// ---------------------------------------------------------------- CSR build
__global__ void deg_kernel(const int* __restrict__ dst, int* __restrict__ deg, int E) {
    int e = blockIdx.x * blockDim.x + threadIdx.x;
    if (e < E) atomicAdd(&deg[dst[e]], 1);
}

__global__ void scan1_kernel(const int* __restrict__ deg, int* __restrict__ pre,
                             int* __restrict__ bsum) {
    __shared__ int sm[256];
    int t = threadIdx.x;
    int i = blockIdx.x * 256 + t;
    int v = (i < NN) ? deg[i] : 0;
    sm[t] = v;
    __syncthreads();
#pragma unroll
    for (int off = 1; off < 256; off <<= 1) {
        int u = (t >= off) ? sm[t - off] : 0;
        __syncthreads();
        sm[t] += u;
        __syncthreads();
    }
    if (i < NN) pre[i] = sm[t] - v;
    if (t == 255) bsum[blockIdx.x] = sm[255];
}

__global__ void scan2_kernel(const int* __restrict__ bsum, int* __restrict__ boff) {
    __shared__ int sm[256];
    int t = threadIdx.x;
    int v = (t < SCAN_NB) ? bsum[t] : 0;
    sm[t] = v;
    __syncthreads();
#pragma unroll
    for (int off = 1; off < 256; off <<= 1) {
        int u = (t >= off) ? sm[t - off] : 0;
        __syncthreads();
        sm[t] += u;
        __syncthreads();
    }
    if (t < SCAN_NB) boff[t] = sm[t] - v;
}

__global__ void scan3_kernel(int* __restrict__ row_start, const int* __restrict__ boff,
                             int* __restrict__ cursor) {
    int i = blockIdx.x * 256 + threadIdx.x;
    if (i < NN) {
        int r = row_start[i] + boff[blockIdx.x];
        row_start[i] = r;
        cursor[i] = r;
    }
    if (i == 0) row_start[NN] = NE;
}

// fill CSR: also permute edge_attr into CSR order (contiguous later)
__global__ void fill_kernel(const int* __restrict__ src, const int* __restrict__ dst,
                            const float* __restrict__ ea, int* __restrict__ cursor,
                            int* __restrict__ csr_src, float* __restrict__ ea_perm, int E) {
    int e = blockIdx.x * blockDim.x + threadIdx.x;
    if (e < E) {
        int d = dst[e];
        int p = atomicAdd(&cursor[d], 1);
        csr_src[p] = src[e];
        const float4* q = reinterpret_cast<const float4*>(ea + (size_t)e * 8);
        float4* o = reinterpret_cast<float4*>(ea_perm + (size_t)p * 8);
        float4 q0 = q[0], q1 = q[1];
        o[0] = q0; o[1] = q1;
    }
}

// ---------------------------------------------------------------- agg_e (contiguous)
__global__ void agge_kernel(const float* __restrict__ ea_perm, const int* __restrict__ row_start,
                            float* __restrict__ aggE) {
    int v = blockIdx.x * blockDim.x + threadIdx.x;
    if (v >= NN) return;
    int lo = row_start[v], hi = row_start[v + 1];
    float4 a0 = {0.f,0.f,0.f,0.f}, a1 = {0.f,0.f,0.f,0.f};
    float4 b0 = {0.f,0.f,0.f,0.f}, b1 = {0.f,0.f,0.f,0.f};
    const float4* P = reinterpret_cast<const float4*>(ea_perm);
    int j = lo;
    for (; j + 2 <= hi; j += 2) {
        float4 u0 = P[(size_t)j * 2 + 0], u1 = P[(size_t)j * 2 + 1];
        float4 u2 = P[(size_t)j * 2 + 2], u3 = P[(size_t)j * 2 + 3];
        a0.x += u0.x; a0.y += u0.y; a0.z += u0.z; a0.w += u0.w;
        a1.x += u1.x; a1.y += u1.y; a1.z += u1.z; a1.w += u1.w;
        b0.x += u2.x; b0.y += u2.y; b0.z += u2.z; b0.w += u2.w;
        b1.x += u3.x; b1.y += u3.y; b1.z += u3.z; b1.w += u3.w;
    }
    if (j < hi) {
        float4 u0 = P[(size_t)j * 2 + 0], u1 = P[(size_t)j * 2 + 1];
        a0.x += u0.x; a0.y += u0.y; a0.z += u0.z; a0.w += u0.w;
        a1.x += u1.x; a1.y += u1.y; a1.z += u1.z; a1.w += u1.w;
    }
    a0.x += b0.x; a0.y += b0.y; a0.z += b0.z; a0.w += b0.w;
    a1.x += b1.x; a1.y += b1.y; a1.z += b1.z; a1.w += b1.w;
    float4* o = reinterpret_cast<float4*>(aggE + (size_t)v * 8);
    o[0] = a0; o[1] = a1;
}

// ---------------------------------------------------------------- agg_h (per layer)
// wave per node; indices batch-loaded (coalesced) and broadcast via shfl;
// 4 gather loads in flight.
template <int DIN>
__global__ void aggh_kernel(const float* __restrict__ h, const int* __restrict__ row_start,
                            const int* __restrict__ csrc, float* __restrict__ aggH) {
    int w = blockIdx.x * (blockDim.x >> 6) + (threadIdx.x >> 6);
    int lane = threadIdx.x & 63;
    if (w >= NN) return;
    int lo = row_start[w], hi = row_start[w + 1];

    if constexpr (DIN == 128) {
        const float2* H = reinterpret_cast<const float2*>(h);
        float2 a0 = {0.f,0.f}, a1 = {0.f,0.f}, a2 = {0.f,0.f}, a3 = {0.f,0.f};
        int j = lo;
        while (j < hi) {
            int cnt = hi - j; if (cnt > 64) cnt = 64;
            int myidx = (lane < cnt) ? csrc[j + lane] : 0;
            int k = 0;
            for (; k + 4 <= cnt; k += 4) {
                int s0 = __shfl(myidx, k);
                int s1 = __shfl(myidx, k + 1);
                int s2 = __shfl(myidx, k + 2);
                int s3 = __shfl(myidx, k + 3);
                float2 v0 = H[(size_t)s0 * 64 + lane];
                float2 v1 = H[(size_t)s1 * 64 + lane];
                float2 v2 = H[(size_t)s2 * 64 + lane];
                float2 v3 = H[(size_t)s3 * 64 + lane];
                a0.x += v0.x; a0.y += v0.y;
                a1.x += v1.x; a1.y += v1.y;
                a2.x += v2.x; a2.y += v2.y;
                a3.x += v3.x; a3.y += v3.y;
            }
            for (; k < cnt; ++k) {
                int s = __shfl(myidx, k);
                float2 v = H[(size_t)s * 64 + lane];
                a0.x += v.x; a0.y += v.y;
            }
            j += cnt;
        }
        a0.x += a1.x; a0.y += a1.y;
        a2.x += a3.x; a2.y += a3.y;
        a0.x += a2.x; a0.y += a2.y;
        reinterpret_cast<float2*>(aggH)[(size_t)w * 64 + lane] = a0;
    } else if constexpr (DIN == 64) {
        float a0 = 0.f, a1 = 0.f, a2 = 0.f, a3 = 0.f;
        int j = lo;
        while (j < hi) {
            int cnt = hi - j; if (cnt > 64) cnt = 64;
            int myidx = (lane < cnt) ? csrc[j + lane] : 0;
            int k = 0;
            for (; k + 4 <= cnt; k += 4) {
                int s0 = __shfl(myidx, k);
                int s1 = __shfl(myidx, k + 1);
                int s2 = __shfl(myidx, k + 2);
                int s3 = __shfl(myidx, k + 3);
                a0 += h[(size_t)s0 * 64 + lane];
                a1 += h[(size_t)s1 * 64 + lane];
                a2 += h[(size_t)s2 * 64 + lane];
                a3 += h[(size_t)s3 * 64 + lane];
            }
            for (; k < cnt; ++k) {
                int s = __shfl(myidx, k);
                a0 += h[(size_t)s * 64 + lane];
            }
            j += cnt;
        }
        aggH[(size_t)w * 64 + lane] = (a0 + a1) + (a2 + a3);
    } else {  // DIN == 32: lanes 0-31 = even edge, lanes 32-63 = odd edge
        int half = lane >> 5;
        int l32 = lane & 31;
        float a0 = 0.f, a1 = 0.f, a2 = 0.f, a3 = 0.f;
        int j = lo;
        while (j < hi) {
            int cnt = hi - j; if (cnt > 64) cnt = 64;
            int myidx = (lane < cnt) ? csrc[j + lane] : 0;
            int k = 0;
            for (; k + 8 <= cnt; k += 8) {
                int s0 = __shfl(myidx, k + half);
                int s1 = __shfl(myidx, k + 2 + half);
                int s2 = __shfl(myidx, k + 4 + half);
                int s3 = __shfl(myidx, k + 6 + half);
                a0 += h[(size_t)s0 * 32 + l32];
                a1 += h[(size_t)s1 * 32 + l32];
                a2 += h[(size_t)s2 * 32 + l32];
                a3 += h[(size_t)s3 * 32 + l32];
            }
            for (; k + 2 <= cnt; k += 2) {
                int s = __shfl(myidx, k + half);
                a0 += h[(size_t)s * 32 + l32];
            }
            if (k < cnt) {  // odd tail: half 0 only
                int s = __shfl(myidx, k);
                if (half == 0) a1 += h[(size_t)s * 32 + l32];
            }
            j += cnt;
        }
        a0 = (a0 + a1) + (a2 + a3);
        a0 += __shfl_xor(a0, 32);
        if (lane < 32) aggH[(size_t)w * 32 + lane] = a0;
    }
}

// ---------------------------------------------------------------- fused dense layer
// out = relu( h@Ws + aggH@Wm[0:DIN] + aggE@Wm[DIN:DIN+8] + b )
template <int DIN, int DOUT>
__global__ __launch_bounds__(256) void dense_kernel(
    const float* __restrict__ h, const float* __restrict__ aggH, const float* __restrict__ aggE,
    const float* __restrict__ Ws, const float* __restrict__ Wm, const float* __restrict__ b,
    float* __restrict__ out) {
    constexpr int NCH = DIN / 16;        // 2*DIN/32 chunks over [h | aggH]
    constexpr int HCH = DIN / 32;
    constexpr int TN = DOUT / 16;
    constexpr int NV = TN / 4;

    __shared__ float Xs[64][36];
    __shared__ float Wt[32][DOUT];
    __shared__ float Es[64][8];
    __shared__ float We[8][DOUT];

    const int t = threadIdx.x;
    const int tn = t & 15, tm = t >> 4;
    const int row0 = blockIdx.x * 64;

    if (t < 128) {
        int r = t >> 1, c4 = (t & 1) * 4;
        int row = row0 + r;
        float4 v = {0.f, 0.f, 0.f, 0.f};
        if (row < NN) v = *reinterpret_cast<const float4*>(&aggE[(size_t)row * 8 + c4]);
        *reinterpret_cast<float4*>(&Es[r][c4]) = v;
    }
    {
        constexpr int WE_F4 = 8 * DOUT / 4;
        if (t < WE_F4) {
            int k = t / (DOUT / 4), c4 = (t % (DOUT / 4)) * 4;
            *reinterpret_cast<float4*>(&We[k][c4]) =
                *reinterpret_cast<const float4*>(&Wm[(size_t)(DIN + k) * DOUT + c4]);
        }
    }

    float4 bv[NV];
#pragma unroll
    for (int g = 0; g < NV; ++g)
        bv[g] = *reinterpret_cast<const float4*>(&b[g * 64 + tn * 4]);

    float acc[4][TN];
#pragma unroll
    for (int r = 0; r < 4; ++r)
#pragma unroll
        for (int c = 0; c < TN; ++c) acc[r][c] = 0.f;

    for (int ch = 0; ch < NCH; ++ch) {
        const bool isH = (ch < HCH);
        const float* xsrc = isH ? h : aggH;
        const int koff = (isH ? ch : ch - HCH) * 32;
        const float* wsrc = isH ? (Ws + (size_t)(ch * 32) * DOUT)
                                : (Wm + (size_t)((ch - HCH) * 32) * DOUT);
#pragma unroll
        for (int rep = 0; rep < 2; ++rep) {
            int f4 = rep * 256 + t;
            int r = f4 >> 3, kof = (f4 & 7) * 4;
            int row = row0 + r;
            float4 v = {0.f, 0.f, 0.f, 0.f};
            if (row < NN)
                v = *reinterpret_cast<const float4*>(&xsrc[(size_t)row * DIN + koff + kof]);
            *reinterpret_cast<float4*>(&Xs[r][kof]) = v;
        }
        constexpr int W_F4 = 32 * DOUT / 4;
#pragma unroll
        for (int rep = 0; rep < W_F4 / 256; ++rep) {
            int f4 = rep * 256 + t;
            int k = f4 / (DOUT / 4), c4 = (f4 % (DOUT / 4)) * 4;
            *reinterpret_cast<float4*>(&Wt[k][c4]) =
                *reinterpret_cast<const float4*>(&wsrc[(size_t)k * DOUT + c4]);
        }
        __syncthreads();
#pragma unroll
        for (int k = 0; k < 32; ++k) {
            float xv[4];
#pragma unroll
            for (int r = 0; r < 4; ++r) xv[r] = Xs[tm * 4 + r][k];
            float4 wv[NV];
#pragma unroll
            for (int g = 0; g < NV; ++g)
                wv[g] = *reinterpret_cast<const float4*>(&Wt[k][g * 64 + tn * 4]);
#pragma unroll
            for (int r = 0; r < 4; ++r)
#pragma unroll
                for (int g = 0; g < NV; ++g) {
                    acc[r][g * 4 + 0] += xv[r] * wv[g].x;
                    acc[r][g * 4 + 1] += xv[r] * wv[g].y;
                    acc[r][g * 4 + 2] += xv[r] * wv[g].z;
                    acc[r][g * 4 + 3] += xv[r] * wv[g].w;
                }
        }
        __syncthreads();
    }

#pragma unroll
    for (int j = 0; j < 8; ++j) {
        float xv[4];
#pragma unroll
        for (int r = 0; r < 4; ++r) xv[r] = Es[tm * 4 + r][j];
        float4 wv[NV];
#pragma unroll
        for (int g = 0; g < NV; ++g)
            wv[g] = *reinterpret_cast<const float4*>(&We[j][g * 64 + tn * 4]);
#pragma unroll
        for (int r = 0; r < 4; ++r)
#pragma unroll
            for (int g = 0; g < NV; ++g) {
                acc[r][g * 4 + 0] += xv[r] * wv[g].x;
                acc[r][g * 4 + 1] += xv[r] * wv[g].y;
                acc[r][g * 4 + 2] += xv[r] * wv[g].z;
                acc[r][g * 4 + 3] += xv[r] * wv[g].w;
            }
    }

#pragma unroll
    for (int r = 0; r < 4; ++r) {
        int row = row0 + tm * 4 + r;
        if (row < NN) {
#pragma unroll
            for (int g = 0; g < NV; ++g) {
                float4 o;
                o.x = acc[r][g * 4 + 0] + bv[g].x;
                o.y = acc[r][g * 4 + 1] + bv[g].y;
                o.z = acc[r][g * 4 + 2] + bv[g].z;
                o.w = acc[r][g * 4 + 3] + bv[g].w;
                o.x = o.x > 0.f ? o.x : 0.f;
                o.y = o.y > 0.f ? o.y : 0.f;
                o.z = o.z > 0.f ? o.z : 0.f;
                o.w = o.w > 0.f ? o.w : 0.f;
                *reinterpret_cast<float4*>(&out[(size_t)row * DOUT + g * 64 + tn * 4]) = o;
            }
        }
    }
}

// ---------------------------------------------------------------- final linear
__global__ void final_kernel(const float* __restrict__ h, const float* __restrict__ Wc,
                             const float* __restrict__ bc, float* __restrict__ out) {
    int w = blockIdx.x * (blockDim.x >> 6) + (threadIdx.x >> 6);
    int lane = threadIdx.x & 63;
    if (w >= NN) return;
    const float2* H = reinterpret_cast<const float2*>(h);
    const float2* W = reinterpret_cast<const float2*>(Wc);
    float2 hv = H[(size_t)w * 64 + lane];
    float2 wv = W[lane];
    float p = hv.x * wv.x + hv.y * wv.y;
#pragma unroll
    for (int off = 32; off; off >>= 1) p += __shfl_down(p, off);
    if (lane == 0) out[w] = p + bc[0];
}

// ---------------------------------------------------------------- launch
extern "C" void kernel_launch(void* const* d_in, const int* in_sizes, int n_in,
                              void* d_out, int out_size, void* d_ws, size_t ws_size,
                              hipStream_t stream) {
    const float* x   = (const float*)d_in[0];
    const float* ea  = (const float*)d_in[1];
    const int*   src = (const int*)d_in[2];
    const int*   dst = (const int*)d_in[3];
    const float* Ws[5]; const float* Wm[5]; const float* bb[5];
    for (int i = 0; i < 5; ++i) {
        Ws[i] = (const float*)d_in[4 + 3 * i];
        Wm[i] = (const float*)d_in[5 + 3 * i];
        bb[i] = (const float*)d_in[6 + 3 * i];
    }
    const float* Wc = (const float*)d_in[19];
    const float* bc = (const float*)d_in[20];
    float* out = (float*)d_out;

    size_t off = 0;
    auto alloc = [&](size_t bytes) {
        void* p = (char*)d_ws + off;
        off += (bytes + 255) & ~(size_t)255;
        return p;
    };
    float* hA        = (float*)alloc((size_t)NN * 128 * 4);
    float* hB        = (float*)alloc((size_t)NN * 128 * 4);
    float* aggH      = (float*)alloc((size_t)NN * 128 * 4);
    float* aggE      = (float*)alloc((size_t)NN * 8 * 4);
    int*   deg       = (int*)alloc((size_t)(NN + 1) * 4);
    int*   row_start = (int*)alloc((size_t)(NN + 1) * 4);
    int*   cursor    = (int*)alloc((size_t)NN * 4);
    int*   csr_src   = (int*)alloc((size_t)NE * 4);
    int*   bsum      = (int*)alloc((size_t)SCAN_NB * 4);
    int*   boff      = (int*)alloc((size_t)SCAN_NB * 4);
    // ea_perm aliases hB: dead before hB is first written (layer-1 dense)
    float* ea_perm   = hB;
    (void)ws_size; (void)in_sizes; (void)n_in; (void)out_size;

    zero_int_kernel<<<(NN + 255) / 256, 256, 0, stream>>>(deg, NN);
    deg_kernel<<<(NE + 255) / 256, 256, 0, stream>>>(dst, deg, NE);
    scan1_kernel<<<SCAN_NB, 256, 0, stream>>>(deg, row_start, bsum);
    scan2_kernel<<<1, 256, 0, stream>>>(bsum, boff);
    scan3_kernel<<<SCAN_NB, 256, 0, stream>>>(row_start, boff, cursor);
    fill_kernel<<<(NE + 255) / 256, 256, 0, stream>>>(src, dst, ea, cursor, csr_src, ea_perm, NE);

    agge_kernel<<<(NN + 255) / 256, 256, 0, stream>>>(ea_perm, row_start, aggE);

    const int GRID_W = (NN + 3) / 4;
    const int GRID_D = (NN + 63) / 64;

    aggh_kernel<32><<<GRID_W, 256, 0, stream>>>(x, row_start, csr_src, aggH);
    dense_kernel<32, 64><<<GRID_D, 256, 0, stream>>>(x, aggH, aggE, Ws[0], Wm[0], bb[0], hA);

    aggh_kernel<64><<<GRID_W, 256, 0, stream>>>(hA, row_start, csr_src, aggH);
    dense_kernel<64, 128><<<GRID_D, 256, 0, stream>>>(hA, aggH, aggE, Ws[1], Wm[1], bb[1], hB);

    aggh_kernel<128><<<GRID_W, 256, 0, stream>>>(hB, row_start, csr_src, aggH);
    dense_kernel<128, 128><<<GRID_D, 256, 0, stream>>>(hB, aggH, aggE, Ws[2], Wm[2], bb[2], hA);

    aggh_kernel<128><<<GRID_W, 256, 0, stream>>>(hA, row_start, csr_src, aggH);
    dense_kernel<128, 128><<<GRID_D, 256, 0, stream>>>(hA, aggH, aggE, Ws[3], Wm[3], bb[3], hB);

    aggh_kernel<128><<<GRID_W, 256, 0, stream>>>(hB, row_start, csr_src, aggH);
    dense_kernel<128, 128><<<GRID_D, 256, 0, stream>>>(hB, aggH, aggE, Ws[4], Wm[4], bb[4], hA);

    final_kernel<<<GRID_W, 256, 0, stream>>>(hA, Wc, bc, out);
}

// Round 7
// 525.282 us; speedup vs baseline: 3.7296x; 1.0547x over previous
//
#include <hip/hip_runtime.h>
#include <hip/hip_bf16.h>

#define NN 50000
#define NE 800000
#define SCAN_NB ((NN + 255) / 256)   // 196

typedef __attribute__((ext_vector_type(8))) short bf16x8;
typedef __attribute__((ext_vector_type(4))) float f32x4;

__device__ __forceinline__ ushort f2bf(float f) {
    __hip_bfloat16 h = __float2bfloat16(f);
    return *reinterpret_cast<ushort*>(&h);
}
__device__ __forceinline__ float bf2f(ushort u) {
    return __builtin_bit_cast(float, (uint)u << 16);
}
// pack split hi/lo bf16 of (a,b) into two uints (little-endian ushort pairs)
__device__ __forceinline__ void split2(float a, float b, uint& hi, uint& lo) {
    ushort ha = f2bf(a), hb = f2bf(b);
    float fa = bf2f(ha), fb = bf2f(hb);
    ushort la = f2bf(a - fa), lb = f2bf(b - fb);
    hi = (uint)ha | ((uint)hb << 16);
    lo = (uint)la | ((uint)lb << 16);
}

// ---------------------------------------------------------------- utilities
__global__ void zero_int_kernel(int* __restrict__ p, int n) {
    int i = blockIdx.x * blockDim.x + threadIdx.x;
    if (i < n) p[i] = 0;
}

// W split into hi/lo bf16 planes: [c][k]; k<DIN -> Ws[k][c]; else Wm[k-DIN][c]; pad 0
__global__ void prep_w_kernel(const float* __restrict__ Ws, const float* __restrict__ Wm,
                              ushort* __restrict__ Whi, ushort* __restrict__ Wlo,
                              int DIN, int DOUT, int KPAD) {
    int gid = blockIdx.x * blockDim.x + threadIdx.x;
    if (gid >= DOUT * KPAD) return;
    int c = gid / KPAD, k = gid % KPAD;
    float v = 0.f;
    if (k < DIN) v = Ws[(size_t)k * DOUT + c];
    else if (k < 2 * DIN + 8) v = Wm[(size_t)(k - DIN) * DOUT + c];
    ushort h = f2bf(v);
    Whi[gid] = h;
    Wlo[gid] = f2bf(v - bf2f(h));
}

// ---------------------------------------------------------------- CSR build
__global__ void deg_kernel(const int* __restrict__ dst, int* __restrict__ deg, int E) {
    int e = blockIdx.x * blockDim.x + threadIdx.x;
    if (e < E) atomicAdd(&deg[dst[e]], 1);
}

__global__ void scan1_kernel(const int* __restrict__ deg, int* __restrict__ pre,
                             int* __restrict__ bsum) {
    __shared__ int sm[256];
    int t = threadIdx.x;
    int i = blockIdx.x * 256 + t;
    int v = (i < NN) ? deg[i] : 0;
    sm[t] = v;
    __syncthreads();
#pragma unroll
    for (int off = 1; off < 256; off <<= 1) {
        int u = (t >= off) ? sm[t - off] : 0;
        __syncthreads();
        sm[t] += u;
        __syncthreads();
    }
    if (i < NN) pre[i] = sm[t] - v;
    if (t == 255) bsum[blockIdx.x] = sm[255];
}

__global__ void scan2_kernel(const int* __restrict__ bsum, int* __restrict__ boff) {
    __shared__ int sm[256];
    int t = threadIdx.x;
    int v = (t < SCAN_NB) ? bsum[t] : 0;
    sm[t] = v;
    __syncthreads();
#pragma unroll
    for (int off = 1; off < 256; off <<= 1) {
        int u = (t >= off) ? sm[t - off] : 0;
        __syncthreads();
        sm[t] += u;
        __syncthreads();
    }
    if (t < SCAN_NB) boff[t] = sm[t] - v;
}

__global__ void scan3_kernel(int* __restrict__ row_start, const int* __restrict__ boff,
                             int* __restrict__ cursor) {
    int i = blockIdx.x * 256 + threadIdx.x;
    if (i < NN) {
        int r = row_start[i] + boff[blockIdx.x];
        row_start[i] = r;
        cursor[i] = r;
    }
    if (i == 0) row_start[NN] = NE;
}

// fill CSR; permute edge_attr into CSR order (fp32)
__global__ void fill_kernel(const int* __restrict__ src, const int* __restrict__ dst,
                            const float* __restrict__ ea, int* __restrict__ cursor,
                            int* __restrict__ csr_src, float* __restrict__ ea_perm, int E) {
    int e = blockIdx.x * blockDim.x + threadIdx.x;
    if (e < E) {
        int d = dst[e];
        int p = atomicAdd(&cursor[d], 1);
        csr_src[p] = src[e];
        const float4* q = reinterpret_cast<const float4*>(ea + (size_t)e * 8);
        float4 q0 = q[0], q1 = q[1];
        float4* o = reinterpret_cast<float4*>(ea_perm + (size_t)p * 8);
        o[0] = q0; o[1] = q1;
    }
}

// ---------------------------------------------------------------- agg_e (contiguous fp32)
__global__ void agge_kernel(const float* __restrict__ ea_perm, const int* __restrict__ row_start,
                            float* __restrict__ aggE) {
    int v = blockIdx.x * blockDim.x + threadIdx.x;
    if (v >= NN) return;
    int lo = row_start[v], hi = row_start[v + 1];
    float4 a0 = {0.f,0.f,0.f,0.f}, a1 = {0.f,0.f,0.f,0.f};
    float4 b0 = {0.f,0.f,0.f,0.f}, b1 = {0.f,0.f,0.f,0.f};
    const float4* P = reinterpret_cast<const float4*>(ea_perm);
    int j = lo;
    for (; j + 2 <= hi; j += 2) {
        float4 u0 = P[(size_t)j * 2 + 0], u1 = P[(size_t)j * 2 + 1];
        float4 u2 = P[(size_t)j * 2 + 2], u3 = P[(size_t)j * 2 + 3];
        a0.x += u0.x; a0.y += u0.y; a0.z += u0.z; a0.w += u0.w;
        a1.x += u1.x; a1.y += u1.y; a1.z += u1.z; a1.w += u1.w;
        b0.x += u2.x; b0.y += u2.y; b0.z += u2.z; b0.w += u2.w;
        b1.x += u3.x; b1.y += u3.y; b1.z += u3.z; b1.w += u3.w;
    }
    if (j < hi) {
        float4 u0 = P[(size_t)j * 2 + 0], u1 = P[(size_t)j * 2 + 1];
        a0.x += u0.x; a0.y += u0.y; a0.z += u0.z; a0.w += u0.w;
        a1.x += u1.x; a1.y += u1.y; a1.z += u1.z; a1.w += u1.w;
    }
    a0.x += b0.x; a0.y += b0.y; a0.z += b0.z; a0.w += b0.w;
    a1.x += b1.x; a1.y += b1.y; a1.z += b1.z; a1.w += b1.w;
    float4* o = reinterpret_cast<float4*>(aggE + (size_t)v * 8);
    o[0] = a0; o[1] = a1;
}

// ---------------------------------------------------------------- agg_h (fp32, batched indices)
template <int DIN>
__global__ void aggh_kernel(const float* __restrict__ h, const int* __restrict__ row_start,
                            const int* __restrict__ csrc, float* __restrict__ aggH) {
    int w = blockIdx.x * (blockDim.x >> 6) + (threadIdx.x >> 6);
    int lane = threadIdx.x & 63;
    if (w >= NN) return;
    int lo = row_start[w], hi = row_start[w + 1];

    if constexpr (DIN == 128) {
        const float2* H = reinterpret_cast<const float2*>(h);
        float2 a0 = {0.f,0.f}, a1 = {0.f,0.f}, a2 = {0.f,0.f}, a3 = {0.f,0.f};
        int j = lo;
        while (j < hi) {
            int cnt = hi - j; if (cnt > 64) cnt = 64;
            int myidx = (lane < cnt) ? csrc[j + lane] : 0;
            int k = 0;
            for (; k + 4 <= cnt; k += 4) {
                int s0 = __shfl(myidx, k);
                int s1 = __shfl(myidx, k + 1);
                int s2 = __shfl(myidx, k + 2);
                int s3 = __shfl(myidx, k + 3);
                float2 v0 = H[(size_t)s0 * 64 + lane];
                float2 v1 = H[(size_t)s1 * 64 + lane];
                float2 v2 = H[(size_t)s2 * 64 + lane];
                float2 v3 = H[(size_t)s3 * 64 + lane];
                a0.x += v0.x; a0.y += v0.y;
                a1.x += v1.x; a1.y += v1.y;
                a2.x += v2.x; a2.y += v2.y;
                a3.x += v3.x; a3.y += v3.y;
            }
            for (; k < cnt; ++k) {
                int s = __shfl(myidx, k);
                float2 v = H[(size_t)s * 64 + lane];
                a0.x += v.x; a0.y += v.y;
            }
            j += cnt;
        }
        a0.x += a1.x; a0.y += a1.y;
        a2.x += a3.x; a2.y += a3.y;
        a0.x += a2.x; a0.y += a2.y;
        reinterpret_cast<float2*>(aggH)[(size_t)w * 64 + lane] = a0;
    } else if constexpr (DIN == 64) {
        float a0 = 0.f, a1 = 0.f, a2 = 0.f, a3 = 0.f;
        int j = lo;
        while (j < hi) {
            int cnt = hi - j; if (cnt > 64) cnt = 64;
            int myidx = (lane < cnt) ? csrc[j + lane] : 0;
            int k = 0;
            for (; k + 4 <= cnt; k += 4) {
                int s0 = __shfl(myidx, k);
                int s1 = __shfl(myidx, k + 1);
                int s2 = __shfl(myidx, k + 2);
                int s3 = __shfl(myidx, k + 3);
                a0 += h[(size_t)s0 * 64 + lane];
                a1 += h[(size_t)s1 * 64 + lane];
                a2 += h[(size_t)s2 * 64 + lane];
                a3 += h[(size_t)s3 * 64 + lane];
            }
            for (; k < cnt; ++k) {
                int s = __shfl(myidx, k);
                a0 += h[(size_t)s * 64 + lane];
            }
            j += cnt;
        }
        aggH[(size_t)w * 64 + lane] = (a0 + a1) + (a2 + a3);
    } else {  // DIN == 32: lanes 0-31 = even edge, lanes 32-63 = odd edge
        int half = lane >> 5;
        int l32 = lane & 31;
        float a0 = 0.f, a1 = 0.f, a2 = 0.f, a3 = 0.f;
        int j = lo;
        while (j < hi) {
            int cnt = hi - j; if (cnt > 64) cnt = 64;
            int myidx = (lane < cnt) ? csrc[j + lane] : 0;
            int k = 0;
            for (; k + 8 <= cnt; k += 8) {
                int s0 = __shfl(myidx, k + half);
                int s1 = __shfl(myidx, k + 2 + half);
                int s2 = __shfl(myidx, k + 4 + half);
                int s3 = __shfl(myidx, k + 6 + half);
                a0 += h[(size_t)s0 * 32 + l32];
                a1 += h[(size_t)s1 * 32 + l32];
                a2 += h[(size_t)s2 * 32 + l32];
                a3 += h[(size_t)s3 * 32 + l32];
            }
            for (; k + 2 <= cnt; k += 2) {
                int s = __shfl(myidx, k + half);
                a0 += h[(size_t)s * 32 + l32];
            }
            if (k < cnt) {
                int s = __shfl(myidx, k);
                if (half == 0) a1 += h[(size_t)s * 32 + l32];
            }
            j += cnt;
        }
        a0 = (a0 + a1) + (a2 + a3);
        a0 += __shfl_xor(a0, 32);
        if (lane < 32) aggH[(size_t)w * 32 + lane] = a0;
    }
}

// ---------------------------------------------------------------- dense MFMA (split A AND W)
// out = [relu]( [h|aggH|aggE] @ W^T + b ); X,W both split hi/lo bf16:
// acc += al*wh + ah*wl + ah*wh  (al*wl dropped, ~2^-18) -> ~fp32 precision.
template <int DIN, int DOUT, bool RELU>
__global__ __launch_bounds__(256) void dense_mfma(
    const float* __restrict__ h, const float* __restrict__ aggH,
    const float* __restrict__ aggE, const ushort* __restrict__ Whi,
    const ushort* __restrict__ Wlo, const float* __restrict__ bias,
    float* __restrict__ out) {
    constexpr int HCH = DIN / 32;
    constexpr int NCH = 2 * HCH + 1;
    constexpr int KPAD = NCH * 32;
    constexpr int NSUB = DOUT / 16;
    constexpr int WREP = DOUT / 64;
    constexpr int SX = 40;              // LDS stride in ushort

    __shared__ ushort Xhi[64 * SX];
    __shared__ ushort Xlo[64 * SX];
    __shared__ ushort Wh[DOUT * SX];
    __shared__ ushort Wl[DOUT * SX];

    const int t = threadIdx.x;
    const int lane = t & 63, wid = t >> 6;
    const int row0 = blockIdx.x * 64;
    const int rb = wid * 16;

    const int sr = t >> 2, sg = t & 3;  // X staging: row (0..63), 8-float granule (0..3)

    f32x4 acc[NSUB];
#pragma unroll
    for (int s = 0; s < NSUB; ++s) acc[s] = (f32x4){0.f, 0.f, 0.f, 0.f};

    auto loadX = [&](int c, float4& v0, float4& v1) {
        int grow = row0 + sr;
        v0 = (float4){0.f, 0.f, 0.f, 0.f};
        v1 = (float4){0.f, 0.f, 0.f, 0.f};
        if (grow < NN) {
            if (c < HCH) {
                const float* p = h + (size_t)grow * DIN + c * 32 + sg * 8;
                v0 = *reinterpret_cast<const float4*>(p);
                v1 = *reinterpret_cast<const float4*>(p + 4);
            } else if (c < 2 * HCH) {
                const float* p = aggH + (size_t)grow * DIN + (c - HCH) * 32 + sg * 8;
                v0 = *reinterpret_cast<const float4*>(p);
                v1 = *reinterpret_cast<const float4*>(p + 4);
            } else if (sg == 0) {
                const float* p = aggE + (size_t)grow * 8;
                v0 = *reinterpret_cast<const float4*>(p);
                v1 = *reinterpret_cast<const float4*>(p + 4);
            }
        }
    };

    float4 x0, x1;
    loadX(0, x0, x1);
    uint4 wrh[WREP], wrl[WREP];
#pragma unroll
    for (int r = 0; r < WREP; ++r) {
        int idx = r * 256 + t, col = idx >> 2, g = idx & 3;
        wrh[r] = *reinterpret_cast<const uint4*>(Whi + (size_t)col * KPAD + g * 8);
        wrl[r] = *reinterpret_cast<const uint4*>(Wlo + (size_t)col * KPAD + g * 8);
    }

    for (int c = 0; c < NCH; ++c) {
        uint4 hq, lq;
        split2(x0.x, x0.y, hq.x, lq.x);
        split2(x0.z, x0.w, hq.y, lq.y);
        split2(x1.x, x1.y, hq.z, lq.z);
        split2(x1.z, x1.w, hq.w, lq.w);
        *reinterpret_cast<uint4*>(Xhi + sr * SX + sg * 8) = hq;
        *reinterpret_cast<uint4*>(Xlo + sr * SX + sg * 8) = lq;
#pragma unroll
        for (int r = 0; r < WREP; ++r) {
            int idx = r * 256 + t, col = idx >> 2, g = idx & 3;
            *reinterpret_cast<uint4*>(Wh + col * SX + g * 8) = wrh[r];
            *reinterpret_cast<uint4*>(Wl + col * SX + g * 8) = wrl[r];
        }
        if (c + 1 < NCH) {  // prefetch next chunk
            loadX(c + 1, x0, x1);
#pragma unroll
            for (int r = 0; r < WREP; ++r) {
                int idx = r * 256 + t, col = idx >> 2, g = idx & 3;
                wrh[r] = *reinterpret_cast<const uint4*>(
                    Whi + (size_t)col * KPAD + (c + 1) * 32 + g * 8);
                wrl[r] = *reinterpret_cast<const uint4*>(
                    Wlo + (size_t)col * KPAD + (c + 1) * 32 + g * 8);
            }
        }
        __syncthreads();
        const int arow = rb + (lane & 15);
        const int kg = (lane >> 4) * 8;
        bf16x8 ah = *reinterpret_cast<const bf16x8*>(Xhi + arow * SX + kg);
        bf16x8 al = *reinterpret_cast<const bf16x8*>(Xlo + arow * SX + kg);
#pragma unroll
        for (int s = 0; s < NSUB; ++s) {
            int col = s * 16 + (lane & 15);
            bf16x8 wh = *reinterpret_cast<const bf16x8*>(Wh + col * SX + kg);
            bf16x8 wl = *reinterpret_cast<const bf16x8*>(Wl + col * SX + kg);
            acc[s] = __builtin_amdgcn_mfma_f32_16x16x32_bf16(al, wh, acc[s], 0, 0, 0);
            acc[s] = __builtin_amdgcn_mfma_f32_16x16x32_bf16(ah, wl, acc[s], 0, 0, 0);
            acc[s] = __builtin_amdgcn_mfma_f32_16x16x32_bf16(ah, wh, acc[s], 0, 0, 0);
        }
        __syncthreads();
    }

    // epilogue: C/D layout col=lane&15, row=(lane>>4)*4+reg
    const int ocol = lane & 15;
    const int rq = lane >> 4;
#pragma unroll
    for (int s = 0; s < NSUB; ++s) {
        float bv = bias[s * 16 + ocol];
#pragma unroll
        for (int r = 0; r < 4; ++r) {
            int grow = row0 + rb + rq * 4 + r;
            if (grow < NN) {
                float v = acc[s][r] + bv;
                if (RELU) v = v > 0.f ? v : 0.f;
                out[(size_t)grow * DOUT + s * 16 + ocol] = v;
            }
        }
    }
}

// ---------------------------------------------------------------- final linear (fp32 h)
__global__ void final_kernel(const float* __restrict__ h, const float* __restrict__ Wc,
                             const float* __restrict__ bc, float* __restrict__ out) {
    int w = blockIdx.x * (blockDim.x >> 6) + (threadIdx.x >> 6);
    int lane = threadIdx.x & 63;
    if (w >= NN) return;
    const float2* H = reinterpret_cast<const float2*>(h);
    const float2* W = reinterpret_cast<const float2*>(Wc);
    float2 hv = H[(size_t)w * 64 + lane];
    float2 wv = W[lane];
    float p = hv.x * wv.x + hv.y * wv.y;
#pragma unroll
    for (int off = 32; off; off >>= 1) p += __shfl_down(p, off);
    if (lane == 0) out[w] = p + bc[0];
}

// ---------------------------------------------------------------- launch
extern "C" void kernel_launch(void* const* d_in, const int* in_sizes, int n_in,
                              void* d_out, int out_size, void* d_ws, size_t ws_size,
                              hipStream_t stream) {
    const float* x   = (const float*)d_in[0];
    const float* ea  = (const float*)d_in[1];
    const int*   src = (const int*)d_in[2];
    const int*   dst = (const int*)d_in[3];
    const float* Ws[5]; const float* Wm[5]; const float* bb[5];
    for (int i = 0; i < 5; ++i) {
        Ws[i] = (const float*)d_in[4 + 3 * i];
        Wm[i] = (const float*)d_in[5 + 3 * i];
        bb[i] = (const float*)d_in[6 + 3 * i];
    }
    const float* Wc = (const float*)d_in[19];
    const float* bc = (const float*)d_in[20];
    float* out = (float*)d_out;

    size_t off = 0;
    auto alloc = [&](size_t bytes) {
        void* p = (char*)d_ws + off;
        off += (bytes + 255) & ~(size_t)255;
        return p;
    };
    float* hA       = (float*)alloc((size_t)NN * 128 * 4);
    float* hB       = (float*)alloc((size_t)NN * 128 * 4);   // aliases ea_perm
    float* aggH     = (float*)alloc((size_t)NN * 128 * 4);
    float* aggE     = (float*)alloc((size_t)NN * 8 * 4);
    ushort* Wh0     = (ushort*)alloc((size_t)64 * 96 * 2);
    ushort* Wl0     = (ushort*)alloc((size_t)64 * 96 * 2);
    ushort* Wh1     = (ushort*)alloc((size_t)128 * 160 * 2);
    ushort* Wl1     = (ushort*)alloc((size_t)128 * 160 * 2);
    ushort* Wh2     = (ushort*)alloc((size_t)128 * 288 * 2);
    ushort* Wl2     = (ushort*)alloc((size_t)128 * 288 * 2);
    ushort* Wh3     = (ushort*)alloc((size_t)128 * 288 * 2);
    ushort* Wl3     = (ushort*)alloc((size_t)128 * 288 * 2);
    ushort* Wh4     = (ushort*)alloc((size_t)128 * 288 * 2);
    ushort* Wl4     = (ushort*)alloc((size_t)128 * 288 * 2);
    int* deg        = (int*)alloc((size_t)(NN + 1) * 4);
    int* row_start  = (int*)alloc((size_t)(NN + 1) * 4);
    int* cursor     = (int*)alloc((size_t)NN * 4);
    int* csr_src    = (int*)alloc((size_t)NE * 4);
    int* bsum       = (int*)alloc((size_t)SCAN_NB * 4);
    int* boff       = (int*)alloc((size_t)SCAN_NB * 4);
    float* ea_perm  = hB;   // NE*8*4 == NN*128*4; dead before hB first written
    (void)ws_size; (void)in_sizes; (void)n_in; (void)out_size;

    // CSR build
    zero_int_kernel<<<(NN + 255) / 256, 256, 0, stream>>>(deg, NN);
    deg_kernel<<<(NE + 255) / 256, 256, 0, stream>>>(dst, deg, NE);
    scan1_kernel<<<SCAN_NB, 256, 0, stream>>>(deg, row_start, bsum);
    scan2_kernel<<<1, 256, 0, stream>>>(bsum, boff);
    scan3_kernel<<<SCAN_NB, 256, 0, stream>>>(row_start, boff, cursor);
    fill_kernel<<<(NE + 255) / 256, 256, 0, stream>>>(src, dst, ea, cursor, csr_src, ea_perm, NE);

    // weight prep (bf16 hi/lo, transposed, K-padded)
    prep_w_kernel<<<(64 * 96 + 255) / 256, 256, 0, stream>>>(Ws[0], Wm[0], Wh0, Wl0, 32, 64, 96);
    prep_w_kernel<<<(128 * 160 + 255) / 256, 256, 0, stream>>>(Ws[1], Wm[1], Wh1, Wl1, 64, 128, 160);
    prep_w_kernel<<<(128 * 288 + 255) / 256, 256, 0, stream>>>(Ws[2], Wm[2], Wh2, Wl2, 128, 128, 288);
    prep_w_kernel<<<(128 * 288 + 255) / 256, 256, 0, stream>>>(Ws[3], Wm[3], Wh3, Wl3, 128, 128, 288);
    prep_w_kernel<<<(128 * 288 + 255) / 256, 256, 0, stream>>>(Ws[4], Wm[4], Wh4, Wl4, 128, 128, 288);

    agge_kernel<<<(NN + 255) / 256, 256, 0, stream>>>(ea_perm, row_start, aggE);

    const int GRID_W = (NN + 3) / 4;
    const int GRID_D = (NN + 63) / 64;

    // layer 0: 32 -> 64
    aggh_kernel<32><<<GRID_W, 256, 0, stream>>>(x, row_start, csr_src, aggH);
    dense_mfma<32, 64, true><<<GRID_D, 256, 0, stream>>>(x, aggH, aggE, Wh0, Wl0, bb[0], hA);
    // layer 1: 64 -> 128
    aggh_kernel<64><<<GRID_W, 256, 0, stream>>>(hA, row_start, csr_src, aggH);
    dense_mfma<64, 128, true><<<GRID_D, 256, 0, stream>>>(hA, aggH, aggE, Wh1, Wl1, bb[1], hB);
    // layer 2
    aggh_kernel<128><<<GRID_W, 256, 0, stream>>>(hB, row_start, csr_src, aggH);
    dense_mfma<128, 128, true><<<GRID_D, 256, 0, stream>>>(hB, aggH, aggE, Wh2, Wl2, bb[2], hA);
    // layer 3
    aggh_kernel<128><<<GRID_W, 256, 0, stream>>>(hA, row_start, csr_src, aggH);
    dense_mfma<128, 128, true><<<GRID_D, 256, 0, stream>>>(hA, aggH, aggE, Wh3, Wl3, bb[3], hB);
    // layer 4 (relu: feat = relu(h5))
    aggh_kernel<128><<<GRID_W, 256, 0, stream>>>(hB, row_start, csr_src, aggH);
    dense_mfma<128, 128, true><<<GRID_D, 256, 0, stream>>>(hB, aggH, aggE, Wh4, Wl4, bb[4], hA);

    // readout
    final_kernel<<<GRID_W, 256, 0, stream>>>(hA, Wc, bc, out);
}